// Round 5
// baseline (206.873 us; speedup 1.0000x reference)
//
#include <hip/hip_runtime.h>

#define CC 128
#define OO 128
#define HH 64
#define WW 64
#define HW (HH*WW)

typedef __attribute__((ext_vector_type(8))) __bf16 bf16x8;
typedef __attribute__((ext_vector_type(4))) float  f32x4;

// ---------------------------------------------------------------------------
// prep: blocks 0..511  -> BN+ReLU into h NHWC bf16 (block per (b,y), b=blk&7)
//       blocks 512..   -> weight relayouts:
//           wt_bf[kk][o][c]      <- w_dconv[o][c][kk]
//           w_off_b[kk][o<32][c] <- w_off[o][c][ky][kx]  (pad 18->32 with 0)
// ---------------------------------------------------------------------------
__global__ __launch_bounds__(256) void prep(
    const float* __restrict__ x,
    const float* __restrict__ gamma, const float* __restrict__ beta,
    const float* __restrict__ mean,  const float* __restrict__ var,
    const float* __restrict__ w_dconv, const float* __restrict__ w_off,
    __bf16* __restrict__ h,            // [b][y][x][c]
    __bf16* __restrict__ wt_bf,        // [kk][o][c]
    __bf16* __restrict__ w_off_b)      // [kk][32][c]
{
    __shared__ float inv_s[128], bb_s[128];
    __shared__ __bf16 tile[64 * 130];
    int blk = blockIdx.x;
    int tid = threadIdx.x;

    if (blk >= 512) {                  // ---- weight transform part ----
        int idx = (blk - 512) * 256 + tid;
        if (idx < 9 * 128 * 128) {
            int c = idx & 127, o = (idx >> 7) & 127, kk = idx >> 14;
            wt_bf[idx] = (__bf16)w_dconv[(o * 128 + c) * 9 + kk];
        }
        if (idx < 9 * 32 * 128) {
            int c = idx & 127, o = (idx >> 7) & 31, kk = idx >> 12;
            float v = (o < 18) ? w_off[o * 1152 + c * 9 + kk] : 0.f;
            w_off_b[idx] = (__bf16)v;
        }
        return;
    }

    // ---- BN+ReLU part ----
    int b = blk & 7, y = blk >> 3;
    if (tid < 128) {
        float iv = gamma[tid] * rsqrtf(var[tid] + 1e-5f);
        inv_s[tid] = iv;
        bb_s[tid]  = beta[tid] - mean[tid] * iv;
    }
    __syncthreads();

    const float* xb = x + (size_t)b * CC * HW + (size_t)y * WW;
    #pragma unroll
    for (int i = 0; i < 8; ++i) {
        int idx = i * 256 + tid;          // 128c x 16 x-quads
        int c = idx >> 4, x4 = idx & 15;
        float4 v = *(const float4*)(xb + (size_t)c * HW + x4 * 4);
        float iv = inv_s[c], bb = bb_s[c];
        tile[(x4 * 4 + 0) * 130 + c] = (__bf16)fmaxf(v.x * iv + bb, 0.f);
        tile[(x4 * 4 + 1) * 130 + c] = (__bf16)fmaxf(v.y * iv + bb, 0.f);
        tile[(x4 * 4 + 2) * 130 + c] = (__bf16)fmaxf(v.z * iv + bb, 0.f);
        tile[(x4 * 4 + 3) * 130 + c] = (__bf16)fmaxf(v.w * iv + bb, 0.f);
    }
    __syncthreads();

    __bf16* hb = h + ((size_t)b * HW + (size_t)y * WW) * CC;
    #pragma unroll
    for (int i = 0; i < 2; ++i) {
        int idx = i * 256 + tid;          // 64x x 8 c16-groups
        int xx = idx >> 3, c16 = idx & 7;
        const uint* src = (const uint*)&tile[xx * 130 + c16 * 16];
        uint r0 = src[0], r1 = src[1], r2 = src[2], r3 = src[3];
        uint r4 = src[4], r5 = src[5], r6 = src[6], r7 = src[7];
        uint* dst = (uint*)(hb + (size_t)xx * CC + c16 * 16);
        *(uint4*)dst       = (uint4){r0, r1, r2, r3};
        *(uint4*)(dst + 4) = (uint4){r4, r5, r6, r7};
    }
}

// ---------------------------------------------------------------------------
// Wave-autonomous fused offset+deform. Grid = 8b x 64y x 4 x-quads = 2048
// single-wave blocks (64 threads). Each wave owns 16 x-positions (one MFMA
// m-tile) end-to-end:
//   phase A: offset GEMM M=16,N=32,K=1152 — A-frags loaded straight from h
//            (fixed kernel shifts, no halo problem), B-frags from L2-hot
//            w_off_b. NO barriers in the K-loop.
//   exchange: D-layout offsets -> offs_s[oc][x] in wave-private LDS,
//            one single-wave __syncthreads.
//   phase B: deform GEMM M=16,N=128,K=1152 — per (kk,lane): bilinear params
//            recomputed (redundant across quads, ~30 VALU), A-frag built in
//            registers from 4 bf16x8 tap loads + fp32 blend; B-frags from
//            L2/L1-hot wt (identical across co-resident waves).
// Frag layouts (verified R2-R4): A/B [idx=lane&15][k=quad*8+j],
// D row(m)=quad*4+reg, col(n)=lane&15.
// ---------------------------------------------------------------------------
__global__ __launch_bounds__(64) void fused_wave(
    const __bf16* __restrict__ h,        // [b][y][x][c] bf16
    const __bf16* __restrict__ w_off_b,  // [kk][32][128] bf16
    const float* __restrict__ b_off,
    const __bf16* __restrict__ wt,       // [kk][o][c] bf16
    const float* __restrict__ b_dconv,
    float* __restrict__ out)             // NCHW fp32
{
    __shared__ float offs_s[32 * 16];    // [oc][x_local]
    int blk = blockIdx.x;
    int b = blk & 7, y = (blk >> 3) & 63, xq = blk >> 9;
    int lane = threadIdx.x;
    int l15 = lane & 15, quad = lane >> 4;
    int xg = xq * 16 + l15;              // this lane's x (m-index)

    const __bf16* hb = h + (size_t)b * HW * CC;

    // ===================== phase A: offset conv (barrier-free) ==============
    f32x4 oa0 = (f32x4){0.f, 0.f, 0.f, 0.f};
    f32x4 oa1 = (f32x4){0.f, 0.f, 0.f, 0.f};
    #pragma unroll 1
    for (int kk = 0; kk < 9; ++kk) {
        int dy = kk / 3 - 1, dxk = kk % 3 - 1;
        int yy = y + dy;
        int xs = xg + dxk;
        bool ok = (yy >= 0) && (yy < HH) && (xs >= 0) && (xs < WW);
        const __bf16* arow = hb + ((size_t)yy * WW + xs) * CC;
        const __bf16* wk = w_off_b + (size_t)kk * 32 * 128;
        #pragma unroll
        for (int ks = 0; ks < 4; ++ks) {
            int cb = ks * 32 + quad * 8;
            bf16x8 a = {};
            if (ok) a = *(const bf16x8*)(arow + cb);
            bf16x8 b0 = *(const bf16x8*)(wk + l15 * 128 + cb);
            bf16x8 b1 = *(const bf16x8*)(wk + (16 + l15) * 128 + cb);
            oa0 = __builtin_amdgcn_mfma_f32_16x16x32_bf16(a, b0, oa0, 0, 0, 0);
            oa1 = __builtin_amdgcn_mfma_f32_16x16x32_bf16(a, b1, oa1, 0, 0, 0);
        }
    }
    // D rows = x_local (quad*4+r), cols = oc (l15 / 16+l15) -> offs_s[oc][x]
    {
        int oc0 = l15, oc1 = 16 + l15;
        float bias0 = (oc0 < 18) ? b_off[oc0] : 0.f;
        float bias1 = (oc1 < 18) ? b_off[oc1] : 0.f;
        #pragma unroll
        for (int r = 0; r < 4; ++r) {
            offs_s[oc0 * 16 + quad * 4 + r] = oa0[r] + bias0;
            offs_s[oc1 * 16 + quad * 4 + r] = oa1[r] + bias1;
        }
    }
    __syncthreads();                     // single-wave block: ~free

    // ===================== phase B: deformable conv (barrier-free) ==========
    f32x4 acc[8];
    #pragma unroll
    for (int nt = 0; nt < 8; ++nt) acc[nt] = (f32x4){0.f, 0.f, 0.f, 0.f};

    #pragma unroll 1
    for (int kk = 0; kk < 9; ++kk) {
        // bilinear params for this lane's x (redundant across quads)
        float dyf = offs_s[(2 * kk) * 16 + l15];
        float dxf = offs_s[(2 * kk + 1) * 16 + l15];
        float py = dyf + (float)y + (float)(kk / 3 - 1);
        float px = dxf + (float)xg + (float)(kk % 3 - 1);
        float fy = floorf(py), fx = floorf(px);
        int y0 = (int)fy, x0 = (int)fx;
        float wy = py - fy, wx = px - fx;
        int y1 = y0 + 1, x1 = x0 + 1;
        bool vy0 = (y0 >= 0) && (y0 < HH);
        bool vy1 = (y1 >= 0) && (y1 < HH);
        bool vx0 = (x0 >= 0) && (x0 < WW);
        bool vx1 = (x1 >= 0) && (x1 < WW);
        int yc0 = min(max(y0, 0), HH - 1), yc1 = min(max(y1, 0), HH - 1);
        int xc0 = min(max(x0, 0), WW - 1), xc1 = min(max(x1, 0), WW - 1);
        float w0 = (vy0 && vx0) ? (1.f - wy) * (1.f - wx) : 0.f;
        float w1 = (vy0 && vx1) ? (1.f - wy) * wx         : 0.f;
        float w2 = (vy1 && vx0) ? wy * (1.f - wx)         : 0.f;
        float w3 = (vy1 && vx1) ? wy * wx                 : 0.f;
        const __bf16* t0p = hb + ((size_t)yc0 * WW + xc0) * CC;
        const __bf16* t1p = hb + ((size_t)yc0 * WW + xc1) * CC;
        const __bf16* t2p = hb + ((size_t)yc1 * WW + xc0) * CC;
        const __bf16* t3p = hb + ((size_t)yc1 * WW + xc1) * CC;
        const __bf16* wk = wt + (size_t)kk * OO * CC;
        #pragma unroll
        for (int ks = 0; ks < 4; ++ks) {
            int cb = ks * 32 + quad * 8;
            bf16x8 t0 = *(const bf16x8*)(t0p + cb);
            bf16x8 t1 = *(const bf16x8*)(t1p + cb);
            bf16x8 t2 = *(const bf16x8*)(t2p + cb);
            bf16x8 t3 = *(const bf16x8*)(t3p + cb);
            bf16x8 af;
            #pragma unroll
            for (int i = 0; i < 8; ++i) {
                float v = w0 * (float)t0[i] + w1 * (float)t1[i]
                        + w2 * (float)t2[i] + w3 * (float)t3[i];
                af[i] = (__bf16)v;
            }
            #pragma unroll
            for (int nt = 0; nt < 8; ++nt) {
                bf16x8 bfrag = *(const bf16x8*)(wk + (size_t)(nt * 16 + l15) * CC + cb);
                acc[nt] = __builtin_amdgcn_mfma_f32_16x16x32_bf16(af, bfrag, acc[nt], 0, 0, 0);
            }
        }
    }

    // epilogue: D rows x = quad*4+r (contiguous, float4), cols o = nt*16+l15
    size_t ob = (size_t)b * OO * HW + (size_t)y * WW + xq * 16 + quad * 4;
    #pragma unroll
    for (int nt = 0; nt < 8; ++nt) {
        int o = nt * 16 + l15;
        float bias = b_dconv[o];
        float4 r;
        r.x = acc[nt][0] + bias;
        r.y = acc[nt][1] + bias;
        r.z = acc[nt][2] + bias;
        r.w = acc[nt][3] + bias;
        *(float4*)&out[ob + (size_t)o * HW] = r;
    }
}

// ---------------------------------------------------------------------------
extern "C" void kernel_launch(void* const* d_in, const int* in_sizes, int n_in,
                              void* d_out, int out_size, void* d_ws, size_t ws_size,
                              hipStream_t stream)
{
    const float* x       = (const float*)d_in[0];
    const float* gamma   = (const float*)d_in[1];
    const float* beta    = (const float*)d_in[2];
    const float* mean    = (const float*)d_in[3];
    const float* var     = (const float*)d_in[4];
    const float* w_off   = (const float*)d_in[5];
    const float* b_off   = (const float*)d_in[6];
    const float* w_dconv = (const float*)d_in[7];
    const float* b_dconv = (const float*)d_in[8];
    float* out = (float*)d_out;

    char* ws = (char*)d_ws;
    __bf16* h_bf    = (__bf16*)ws;                 // 8,388,608 B
    __bf16* wt_bf   = (__bf16*)(ws + 8388608);     //   294,912 B
    __bf16* w_off_b = (__bf16*)(ws + 8683520);     //    73,728 B

    // 512 bn-blocks + 720 weight-transform blocks in one dispatch
    prep<<<1232, 256, 0, stream>>>(x, gamma, beta, mean, var,
                                   w_dconv, w_off, h_bf, wt_bf, w_off_b);
    fused_wave<<<2048, 64, 0, stream>>>(h_bf, w_off_b, b_off, wt_bf, b_dconv, out);
}

// Round 7
// 133.609 us; speedup vs baseline: 1.5483x; 1.5483x over previous
//
#include <hip/hip_runtime.h>

#define CC 128
#define OO 128
#define HH 64
#define WW 64
#define HW (HH*WW)

typedef __attribute__((ext_vector_type(8))) __bf16 bf16x8;
typedef __attribute__((ext_vector_type(4))) __bf16 bf16x4;
typedef __attribute__((ext_vector_type(4))) float  f32x4;

// ---------------------------------------------------------------------------
// prep (verbatim R5, passed):
//   blocks 0..511  -> BN+ReLU into h NHWC bf16 (block per (b,y), b=blk&7)
//   blocks 512..   -> weight relayouts:
//       wt_bf[kk][o][c]      <- w_dconv[o][c][kk]
//       w_off_b[kk][o<32][c] <- w_off[o][c][ky][kx]  (pad 18->32 with 0)
// ---------------------------------------------------------------------------
__global__ __launch_bounds__(256) void prep(
    const float* __restrict__ x,
    const float* __restrict__ gamma, const float* __restrict__ beta,
    const float* __restrict__ mean,  const float* __restrict__ var,
    const float* __restrict__ w_dconv, const float* __restrict__ w_off,
    __bf16* __restrict__ h,            // [b][y][x][c]
    __bf16* __restrict__ wt_bf,        // [kk][o][c]
    __bf16* __restrict__ w_off_b)      // [kk][32][c]
{
    __shared__ float inv_s[128], bb_s[128];
    __shared__ __bf16 tile[64 * 130];
    int blk = blockIdx.x;
    int tid = threadIdx.x;

    if (blk >= 512) {                  // ---- weight transform part ----
        int idx = (blk - 512) * 256 + tid;
        if (idx < 9 * 128 * 128) {
            int c = idx & 127, o = (idx >> 7) & 127, kk = idx >> 14;
            wt_bf[idx] = (__bf16)w_dconv[(o * 128 + c) * 9 + kk];
        }
        if (idx < 9 * 32 * 128) {
            int c = idx & 127, o = (idx >> 7) & 31, kk = idx >> 12;
            float v = (o < 18) ? w_off[o * 1152 + c * 9 + kk] : 0.f;
            w_off_b[idx] = (__bf16)v;
        }
        return;
    }

    // ---- BN+ReLU part ----
    int b = blk & 7, y = blk >> 3;
    if (tid < 128) {
        float iv = gamma[tid] * rsqrtf(var[tid] + 1e-5f);
        inv_s[tid] = iv;
        bb_s[tid]  = beta[tid] - mean[tid] * iv;
    }
    __syncthreads();

    const float* xb = x + (size_t)b * CC * HW + (size_t)y * WW;
    #pragma unroll
    for (int i = 0; i < 8; ++i) {
        int idx = i * 256 + tid;          // 128c x 16 x-quads
        int c = idx >> 4, x4 = idx & 15;
        float4 v = *(const float4*)(xb + (size_t)c * HW + x4 * 4);
        float iv = inv_s[c], bb = bb_s[c];
        tile[(x4 * 4 + 0) * 130 + c] = (__bf16)fmaxf(v.x * iv + bb, 0.f);
        tile[(x4 * 4 + 1) * 130 + c] = (__bf16)fmaxf(v.y * iv + bb, 0.f);
        tile[(x4 * 4 + 2) * 130 + c] = (__bf16)fmaxf(v.z * iv + bb, 0.f);
        tile[(x4 * 4 + 3) * 130 + c] = (__bf16)fmaxf(v.w * iv + bb, 0.f);
    }
    __syncthreads();

    __bf16* hb = h + ((size_t)b * HW + (size_t)y * WW) * CC;
    #pragma unroll
    for (int i = 0; i < 2; ++i) {
        int idx = i * 256 + tid;          // 64x x 8 c16-groups
        int xx = idx >> 3, c16 = idx & 7;
        const uint* src = (const uint*)&tile[xx * 130 + c16 * 16];
        uint r0 = src[0], r1 = src[1], r2 = src[2], r3 = src[3];
        uint r4 = src[4], r5 = src[5], r6 = src[6], r7 = src[7];
        uint* dst = (uint*)(hb + (size_t)xx * CC + c16 * 16);
        *(uint4*)dst       = (uint4){r0, r1, r2, r3};
        *(uint4*)(dst + 4) = (uint4){r4, r5, r6, r7};
    }
}

// ---------------------------------------------------------------------------
// Offset conv as bf16 MFMA GEMM (verbatim R3, passed): per (b,y) block,
// 64x x 32oc x 1152k. A-chunk per kk: fixed-shift rows of h (zero-masked).
// Frag layouts (verified): A/B [idx=lane&15][k=quad*8+j],
// D row(m)=quad*4+reg, col(n)=lane&15.
// ---------------------------------------------------------------------------
__global__ __launch_bounds__(256) void offset_mfma(
    const __bf16* __restrict__ h,       // [b][y][x][c]
    const __bf16* __restrict__ w_off_b, // [kk][32][128]
    const float* __restrict__ b_off,
    float* __restrict__ offs)           // [b][18][y][x]
{
    __shared__ __align__(16) __bf16 at[64 * 136];
    __shared__ __align__(16) __bf16 bt[32 * 136];
    int blk = blockIdx.x;
    int b = blk & 7, y = blk >> 3;
    int tid = threadIdx.x;
    int lane = tid & 63;
    int wv  = __builtin_amdgcn_readfirstlane(tid >> 6);
    int l15 = lane & 15, quad = lane >> 4;

    const __bf16* hb = h + (size_t)b * HW * CC;

    f32x4 acc[2];
    acc[0] = (f32x4){0.f, 0.f, 0.f, 0.f};
    acc[1] = (f32x4){0.f, 0.f, 0.f, 0.f};

    for (int kk = 0; kk < 9; ++kk) {
        int dy = kk / 3 - 1, dx = kk % 3 - 1;
        int yy = y + dy;
        bool yok = (yy >= 0) && (yy < HH);
        __syncthreads();
        // stage A: 64x x 128c bf16
        #pragma unroll
        for (int i = 0; i < 4; ++i) {
            int idx = i * 256 + tid;
            int xx = idx >> 4, c8 = idx & 15;
            int xs = xx + dx;
            uint4 v = (uint4){0u, 0u, 0u, 0u};
            if (yok && xs >= 0 && xs < WW)
                v = *(const uint4*)(hb + ((size_t)yy * WW + xs) * CC + c8 * 8);
            *(uint4*)&at[xx * 136 + c8 * 8] = v;
        }
        // stage B: 32o x 128c bf16
        const __bf16* wsrc = w_off_b + (size_t)kk * 32 * 128;
        #pragma unroll
        for (int i = 0; i < 2; ++i) {
            int idx = i * 256 + tid;
            int o = idx >> 4, c8 = idx & 15;
            *(uint4*)&bt[o * 136 + c8 * 8] = *(const uint4*)(wsrc + o * 128 + c8 * 8);
        }
        __syncthreads();
        #pragma unroll
        for (int ks = 0; ks < 4; ++ks) {
            int kb = ks * 32 + quad * 8;
            bf16x8 a  = *(const bf16x8*)&at[(wv * 16 + l15) * 136 + kb];
            bf16x8 b0 = *(const bf16x8*)&bt[l15 * 136 + kb];
            bf16x8 b1 = *(const bf16x8*)&bt[(16 + l15) * 136 + kb];
            acc[0] = __builtin_amdgcn_mfma_f32_16x16x32_bf16(a, b0, acc[0], 0, 0, 0);
            acc[1] = __builtin_amdgcn_mfma_f32_16x16x32_bf16(a, b1, acc[1], 0, 0, 0);
        }
    }

    size_t ob = (size_t)b * 18 * HW + (size_t)y * WW;
    #pragma unroll
    for (int nt = 0; nt < 2; ++nt) {
        int oc = nt * 16 + l15;
        if (oc < 18) {
            float bias = b_off[oc];
            #pragma unroll
            for (int r = 0; r < 4; ++r) {
                int xx = wv * 16 + quad * 4 + r;
                offs[ob + (size_t)oc * HW + xx] = acc[nt][r] + bias;
            }
        }
    }
}

// ---------------------------------------------------------------------------
// Deformable conv via bf16 MFMA (verbatim R3, passed). Block per (b,y),
// XCD-swizzled (b = blk&7). h bf16 NHWC -> bf16x4 tap loads.
// ---------------------------------------------------------------------------
__global__ __launch_bounds__(256, 2) void deform_conv_mfma(
    const __bf16* __restrict__ h,      // [b][y][x][c] bf16
    const float* __restrict__ offs,    // [b][18][y][x]
    const __bf16* __restrict__ wt,     // [kk][o][c] bf16
    const float* __restrict__ b_dconv,
    float* __restrict__ out)           // NCHW fp32
{
    __shared__ float pw[576 * 4];
    __shared__ int   pidx[576 * 4];
    __shared__ __align__(16) __bf16 vt[64 * 136];
    __shared__ __align__(16) __bf16 wl[128 * 136];

    int blk = blockIdx.x;
    int b = blk & 7, y = blk >> 3;
    int tid = threadIdx.x;

    const __bf16* hb = h + (size_t)b * HW * CC;
    size_t offbase = (size_t)b * 18 * HW + (size_t)y * WW;

    // ---- phase 0: bilinear params (masked weights + clamped tap offsets) ----
    for (int e = tid; e < 576; e += 256) {
        int kk = e >> 6, xx = e & 63;
        float dy = offs[offbase + (size_t)(2 * kk) * HW + xx];
        float dx = offs[offbase + (size_t)(2 * kk + 1) * HW + xx];
        float py = dy + (float)y + (float)(kk / 3 - 1);
        float px = dx + (float)xx + (float)(kk % 3 - 1);
        float fy = floorf(py), fx = floorf(px);
        int y0 = (int)fy, x0 = (int)fx;
        float wy = py - fy, wx = px - fx;
        int y1 = y0 + 1, x1 = x0 + 1;
        bool vy0 = (y0 >= 0) && (y0 < HH);
        bool vy1 = (y1 >= 0) && (y1 < HH);
        bool vx0 = (x0 >= 0) && (x0 < WW);
        bool vx1 = (x1 >= 0) && (x1 < WW);
        int yc0 = min(max(y0, 0), HH - 1), yc1 = min(max(y1, 0), HH - 1);
        int xc0 = min(max(x0, 0), WW - 1), xc1 = min(max(x1, 0), WW - 1);
        pw[e * 4 + 0] = (vy0 && vx0) ? (1.f - wy) * (1.f - wx) : 0.f;
        pw[e * 4 + 1] = (vy0 && vx1) ? (1.f - wy) * wx         : 0.f;
        pw[e * 4 + 2] = (vy1 && vx0) ? wy * (1.f - wx)         : 0.f;
        pw[e * 4 + 3] = (vy1 && vx1) ? wy * wx                 : 0.f;
        pidx[e * 4 + 0] = (yc0 * WW + xc0) * CC;
        pidx[e * 4 + 1] = (yc0 * WW + xc1) * CC;
        pidx[e * 4 + 2] = (yc1 * WW + xc0) * CC;
        pidx[e * 4 + 3] = (yc1 * WW + xc1) * CC;
    }

    int lane = tid & 63;
    int wv   = __builtin_amdgcn_readfirstlane(tid >> 6);
    int l15  = lane & 15, quad = lane >> 4;
    int cl   = tid & 31, xh = tid >> 5;

    f32x4 acc[4][2];
    #pragma unroll
    for (int mt = 0; mt < 4; ++mt)
        #pragma unroll
        for (int nt = 0; nt < 2; ++nt)
            acc[mt][nt] = (f32x4){0.f, 0.f, 0.f, 0.f};

    for (int kk = 0; kk < 9; ++kk) {
        __syncthreads();
        // ---- stage w chunk: 128o x 128c bf16, 16B coalesced ----
        const uint4* wsrc = (const uint4*)(wt + (size_t)kk * OO * CC);
        #pragma unroll
        for (int j = 0; j < 8; ++j) {
            int idx = j * 256 + tid;
            int cs = idx & 15, o = idx >> 4;
            *(uint4*)&wl[o * 136 + cs * 8] = wsrc[idx];
        }
        // ---- gather v chunk: 64x x 128c; bf16x4 taps, fp32 weighting ----
        #pragma unroll
        for (int j = 0; j < 8; ++j) {
            int xx = xh * 8 + j;
            int e = (kk << 6) + xx;
            float w0 = pw[e * 4 + 0], w1 = pw[e * 4 + 1];
            float w2 = pw[e * 4 + 2], w3 = pw[e * 4 + 3];
            bf16x4 t0 = *(const bf16x4*)(hb + pidx[e * 4 + 0] + cl * 4);
            bf16x4 t1 = *(const bf16x4*)(hb + pidx[e * 4 + 1] + cl * 4);
            bf16x4 t2 = *(const bf16x4*)(hb + pidx[e * 4 + 2] + cl * 4);
            bf16x4 t3 = *(const bf16x4*)(hb + pidx[e * 4 + 3] + cl * 4);
            float rx = w0 * (float)t0[0] + w1 * (float)t1[0] + w2 * (float)t2[0] + w3 * (float)t3[0];
            float ry = w0 * (float)t0[1] + w1 * (float)t1[1] + w2 * (float)t2[1] + w3 * (float)t3[1];
            float rz = w0 * (float)t0[2] + w1 * (float)t1[2] + w2 * (float)t2[2] + w3 * (float)t3[2];
            float rw = w0 * (float)t0[3] + w1 * (float)t1[3] + w2 * (float)t2[3] + w3 * (float)t3[3];
            bf16x4 pk = {(__bf16)rx, (__bf16)ry, (__bf16)rz, (__bf16)rw};
            *(bf16x4*)&vt[xx * 136 + cl * 4] = pk;
        }
        __syncthreads();
        // ---- MFMA: 4 K-steps of 32; wave covers 64x x 32o ----
        #pragma unroll
        for (int ks = 0; ks < 4; ++ks) {
            int kb = ks * 32 + quad * 8;
            bf16x8 a0 = *(const bf16x8*)&vt[(0 * 16 + l15) * 136 + kb];
            bf16x8 a1 = *(const bf16x8*)&vt[(1 * 16 + l15) * 136 + kb];
            bf16x8 a2 = *(const bf16x8*)&vt[(2 * 16 + l15) * 136 + kb];
            bf16x8 a3 = *(const bf16x8*)&vt[(3 * 16 + l15) * 136 + kb];
            bf16x8 b0 = *(const bf16x8*)&wl[(wv * 32 + l15) * 136 + kb];
            bf16x8 b1 = *(const bf16x8*)&wl[(wv * 32 + 16 + l15) * 136 + kb];
            acc[0][0] = __builtin_amdgcn_mfma_f32_16x16x32_bf16(a0, b0, acc[0][0], 0, 0, 0);
            acc[1][0] = __builtin_amdgcn_mfma_f32_16x16x32_bf16(a1, b0, acc[1][0], 0, 0, 0);
            acc[2][0] = __builtin_amdgcn_mfma_f32_16x16x32_bf16(a2, b0, acc[2][0], 0, 0, 0);
            acc[3][0] = __builtin_amdgcn_mfma_f32_16x16x32_bf16(a3, b0, acc[3][0], 0, 0, 0);
            acc[0][1] = __builtin_amdgcn_mfma_f32_16x16x32_bf16(a0, b1, acc[0][1], 0, 0, 0);
            acc[1][1] = __builtin_amdgcn_mfma_f32_16x16x32_bf16(a1, b1, acc[1][1], 0, 0, 0);
            acc[2][1] = __builtin_amdgcn_mfma_f32_16x16x32_bf16(a2, b1, acc[2][1], 0, 0, 0);
            acc[3][1] = __builtin_amdgcn_mfma_f32_16x16x32_bf16(a3, b1, acc[3][1], 0, 0, 0);
        }
    }

    size_t ob = (size_t)b * OO * HW + (size_t)y * WW;
    #pragma unroll
    for (int nt = 0; nt < 2; ++nt) {
        int o = wv * 32 + nt * 16 + l15;
        float bias = b_dconv[o];
        #pragma unroll
        for (int mt = 0; mt < 4; ++mt) {
            int xb = mt * 16 + quad * 4;
            float4 r;
            r.x = acc[mt][nt][0] + bias;
            r.y = acc[mt][nt][1] + bias;
            r.z = acc[mt][nt][2] + bias;
            r.w = acc[mt][nt][3] + bias;
            *(float4*)&out[ob + (size_t)o * HW + xb] = r;
        }
    }
}

// ---------------------------------------------------------------------------
extern "C" void kernel_launch(void* const* d_in, const int* in_sizes, int n_in,
                              void* d_out, int out_size, void* d_ws, size_t ws_size,
                              hipStream_t stream)
{
    const float* x       = (const float*)d_in[0];
    const float* gamma   = (const float*)d_in[1];
    const float* beta    = (const float*)d_in[2];
    const float* mean    = (const float*)d_in[3];
    const float* var     = (const float*)d_in[4];
    const float* w_off   = (const float*)d_in[5];
    const float* b_off   = (const float*)d_in[6];
    const float* w_dconv = (const float*)d_in[7];
    const float* b_dconv = (const float*)d_in[8];
    float* out = (float*)d_out;

    char* ws = (char*)d_ws;
    __bf16* h_bf    = (__bf16*)ws;                 // 8,388,608 B
    float*  offs    = (float*)(ws + 8388608);      // 2,359,296 B
    __bf16* wt_bf   = (__bf16*)(ws + 10747904);    //   294,912 B
    __bf16* w_off_b = (__bf16*)(ws + 11042816);    //    73,728 B

    prep<<<1232, 256, 0, stream>>>(x, gamma, beta, mean, var,
                                   w_dconv, w_off, h_bf, wt_bf, w_off_b);
    offset_mfma<<<512, 256, 0, stream>>>(h_bf, w_off_b, b_off, offs);
    deform_conv_mfma<<<512, 256, 0, stream>>>(h_bf, offs, wt_bf, b_dconv, out);
}